// Round 20
// baseline (59.459 us; speedup 1.0000x reference)
//
#include <hip/hip_runtime.h>

typedef __bf16 bf16x8 __attribute__((ext_vector_type(8)));
typedef __bf16 bf16x4 __attribute__((ext_vector_type(4)));
typedef float f32x16 __attribute__((ext_vector_type(16)));
typedef float f32x4 __attribute__((ext_vector_type(4)));

constexpr int S = 128, R = 256, CM = 256, C = 32, CZ = 128;

#define MFMA __builtin_amdgcn_mfma_f32_32x32x16_bf16

__device__ __forceinline__ bf16x4 cvt4(float a, float b, float c, float d) {
    bf16x4 r;
    r[0] = (__bf16)a; r[1] = (__bf16)b; r[2] = (__bf16)c; r[3] = (__bf16)d;
    return r;
}

// K0: WLRT[c][m], c<32 -> left[m][c], else right[m][c-32] (64 blocks, tiny).
__global__ __launch_bounds__(256) void k_wlr(const float* __restrict__ Lp,
                                             const float* __restrict__ Rp,
                                             __bf16* __restrict__ WLRT) {
    int c = blockIdx.x;
    int m = threadIdx.x;
    const float* src = (c < 32) ? Lp : Rp;
    WLRT[(size_t)c * 256 + m] = (__bf16)src[(size_t)m * 32 + (c & 31)];
}

// K1 merged: blocks 0..1023 = projection (r = b>>2, sq = b&3);
// blocks 1024..1535 = W fragment-pack transpose (independent, consumed by k_main).
__global__ __launch_bounds__(256) void k_projw(const float* __restrict__ msa,
                                               const __bf16* __restrict__ WLRT,
                                               const float* __restrict__ W,
                                               __bf16* __restrict__ aTf,
                                               __bf16* __restrict__ bTf,
                                               __bf16* __restrict__ WTf) {
    const int b = blockIdx.x;
    if (b >= 1024) {
        int g = (b - 1024) * 256 + threadIdx.x;
        int cz = g & 127;
        int k = g >> 7;
        int e = k >> 5, c = k & 31;
        float v = W[(size_t)(c * 32 + e) * 128 + cz];
        WTf[((size_t)(k >> 3) * 128 + cz) * 8 + (k & 7)] = (__bf16)v;
        return;
    }

    __shared__ __align__(16) __bf16 As[32 * 256];       // 16 KB
    __shared__ __align__(16) char Pp[2 * 4096];         // 8 KB partials
    const int r = b >> 2;
    const int sq = b & 3;
    const int t = threadIdx.x;

#pragma unroll
    for (int it = 0; it < 8; ++it) {
        int idx = it * 256 + t;
        int row = idx >> 6;
        int cg = idx & 63;
        float4 v = *(const float4*)&msa[((size_t)(sq * 32 + row) * R + r) * CM + cg * 4];
        bf16x4 h = cvt4(v.x, v.y, v.z, v.w);
        int P = (cg >> 1) ^ (row & 15);
        *(bf16x4*)((char*)As + row * 512 + P * 16 + (cg & 1) * 8) = h;
    }
    __syncthreads();

    const int w = t >> 6;
    const int l = t & 63;
    const int l31 = t & 31;
    const int kh = (t >> 5) & 1;
    const int sd = w & 1;
    const int ksh = w >> 1;

    f32x16 acc;
#pragma unroll
    for (int q = 0; q < 16; ++q) acc[q] = 0.f;

    const bf16x8* wb = (const bf16x8*)&WLRT[(size_t)(sd * 32 + l31) * 256 + 8 * kh];
    const char* arow = (const char*)As + l31 * 512;

    __builtin_amdgcn_s_setprio(1);
#pragma unroll
    for (int j = 0; j < 8; ++j) {
        int ks = ksh * 8 + j;
        int P = (2 * ks + kh) ^ (l31 & 15);
        bf16x8 af = *(const bf16x8*)(arow + P * 16);
        acc = MFMA(af, wb[2 * ks], acc, 0, 0, 0);
    }
    __builtin_amdgcn_s_setprio(0);

    char* pbase = Pp + (size_t)sd * 4096;
    if (ksh == 1) {
#pragma unroll
        for (int pc = 0; pc < 4; ++pc) {
            f32x4 v;
            v[0] = acc[4 * pc + 0]; v[1] = acc[4 * pc + 1];
            v[2] = acc[4 * pc + 2]; v[3] = acc[4 * pc + 3];
            *(f32x4*)(pbase + ((pc * 64) + l) * 16) = v;
        }
    }
    __syncthreads();
    if (ksh == 0) {
#pragma unroll
        for (int pc = 0; pc < 4; ++pc) {
            f32x4 v = *(const f32x4*)(pbase + ((pc * 64) + l) * 16);
            acc[4 * pc + 0] += v[0]; acc[4 * pc + 1] += v[1];
            acc[4 * pc + 2] += v[2]; acc[4 * pc + 3] += v[3];
        }
        __bf16* dst = sd ? bTf : aTf;
#pragma unroll
        for (int q = 0; q < 4; ++q) {
            size_t base = (size_t)r * 4096 + (size_t)(2 * sq + (q >> 1)) * 512 +
                          (size_t)(q & 1) * 256 + (size_t)l31 * 8 + 4 * kh;
            *(bf16x4*)&dst[base] = cvt4(acc[4 * q + 0], acc[4 * q + 1],
                                        acc[4 * q + 2], acc[4 * q + 3]);
        }
    }
}

// K2: 64 pairs (8r x 8t), 512 thr / 8 waves, G in 128 KB LDS.
// Phase A: TWO half-tiles (acc[2][2] = 64 AGPR each); per half, asm-load
// 3-slot window with counted vmcnt(8/4/0) per k-step (phase-B's proven shape).
// W (8 loads) issued in half-1's G-write; lgkm-only barrier keeps them in flight.
// Phase B: r19 verbatim (both M-tiles, K-half split, 8-slot counted-W window).
__global__ __launch_bounds__(512, 2) void k_main(const __bf16* __restrict__ aTf,
                                                 const __bf16* __restrict__ bTf,
                                                 const __bf16* __restrict__ WTf,
                                                 float* __restrict__ out) {
    __shared__ __align__(16) __bf16 Gs[64 * 1024];   // 128 KB

    const int t = threadIdx.x;
    const int w = t >> 6;              // 0..7
    const int l = t & 63;
    const int lane = l & 31;
    const int kh = l >> 5;
    const int r0 = blockIdx.x * 8;
    const int t0 = blockIdx.y * 8;

    const int rg = w & 3;              // A: a-row group
    const int tg = w >> 2;             // A: b-col group (4 cols, split 2+2)
    const int kq = w >> 2;             // B: K-half
    const int ng = w & 3;              // B: cz slice
    const int czl = ng * 32 + lane;
    const char* wbc = (const char*)WTf + ((size_t)kh * 128 + czl) * 16;

    const bf16x8* ap0 = (const bf16x8*)aTf + ((size_t)(r0 + 2 * rg + 0) * 512 + kh * 32 + lane);
    const bf16x8* ap1 = (const bf16x8*)aTf + ((size_t)(r0 + 2 * rg + 1) * 512 + kh * 32 + lane);
    const bf16x8* bc0 = (const bf16x8*)bTf + ((size_t)(t0 + 4 * tg + 0) * 512 + kh * 32 + lane);
    const bf16x8* bc1 = (const bf16x8*)bTf + ((size_t)(t0 + 4 * tg + 1) * 512 + kh * 32 + lane);
    const bf16x8* bc2 = (const bf16x8*)bTf + ((size_t)(t0 + 4 * tg + 2) * 512 + kh * 32 + lane);
    const bf16x8* bc3 = (const bf16x8*)bTf + ((size_t)(t0 + 4 * tg + 3) * 512 + kh * 32 + lane);

    bf16x8 Ah[3][2], Bh[3][2];
    f32x16 acc[2][2];
    bf16x8 Wp[8];

#define ZACC() do { \
    _Pragma("unroll") for (int i = 0; i < 2; ++i) \
    _Pragma("unroll") for (int j = 0; j < 2; ++j) \
    _Pragma("unroll") for (int q = 0; q < 16; ++q) acc[i][j][q] = 0.f; } while (0)

#define ISSA(s, ks, B0, B1) do { \
    asm volatile("global_load_dwordx4 %0, %1, off" : "=v"(Ah[s][0]) : "v"((const void*)(ap0 + (ks) * 64))); \
    asm volatile("global_load_dwordx4 %0, %1, off" : "=v"(Ah[s][1]) : "v"((const void*)(ap1 + (ks) * 64))); \
    asm volatile("global_load_dwordx4 %0, %1, off" : "=v"(Bh[s][0]) : "v"((const void*)((B0) + (ks) * 64))); \
    asm volatile("global_load_dwordx4 %0, %1, off" : "=v"(Bh[s][1]) : "v"((const void*)((B1) + (ks) * 64))); \
} while (0)

#define STEPA(ks, cnt, B0, B1) do { \
    asm volatile("s_waitcnt vmcnt(" #cnt ")"); \
    __builtin_amdgcn_sched_barrier(0); \
    __builtin_amdgcn_s_setprio(1); \
    acc[0][0] = MFMA(Ah[(ks) % 3][0], Bh[(ks) % 3][0], acc[0][0], 0, 0, 0); \
    acc[0][1] = MFMA(Ah[(ks) % 3][0], Bh[(ks) % 3][1], acc[0][1], 0, 0, 0); \
    acc[1][0] = MFMA(Ah[(ks) % 3][1], Bh[(ks) % 3][0], acc[1][0], 0, 0, 0); \
    acc[1][1] = MFMA(Ah[(ks) % 3][1], Bh[(ks) % 3][1], acc[1][1], 0, 0, 0); \
    __builtin_amdgcn_s_setprio(0); \
    if ((ks) + 3 < 8) ISSA((ks) % 3, (ks) + 3, B0, B1); \
} while (0)

    // ---------------- Phase A, half 0 (cols 0,1) ----------------
    ZACC();
    ISSA(0, 0, bc0, bc1); ISSA(1, 1, bc0, bc1); ISSA(2, 2, bc0, bc1);
    STEPA(0, 8, bc0, bc1); STEPA(1, 8, bc0, bc1); STEPA(2, 8, bc0, bc1);
    STEPA(3, 8, bc0, bc1); STEPA(4, 8, bc0, bc1); STEPA(5, 8, bc0, bc1);
    STEPA(6, 4, bc0, bc1); STEPA(7, 0, bc0, bc1);

    // G-write half 0: p = (2rg+i)*8 + 4tg + j
#pragma unroll
    for (int i = 0; i < 2; ++i) {
#pragma unroll
        for (int j = 0; j < 2; ++j) {
            int p = (2 * rg + i) * 8 + 4 * tg + j;
            unsigned prow = (unsigned)p * 2048;
#pragma unroll
            for (int q = 0; q < 4; ++q) {
                int Lc = lane * 4 + q;
                int P = Lc ^ (p & 15) ^ (lane & 7);
                *(bf16x4*)((char*)Gs + prow + (unsigned)P * 16 + kh * 8) =
                    cvt4(acc[i][j][4 * q + 0], acc[i][j][4 * q + 1],
                         acc[i][j][4 * q + 2], acc[i][j][4 * q + 3]);
            }
        }
    }

    // ---------------- Phase A, half 1 (cols 2,3) ----------------
    ZACC();
    ISSA(0, 0, bc2, bc3); ISSA(1, 1, bc2, bc3); ISSA(2, 2, bc2, bc3);
    STEPA(0, 8, bc2, bc3); STEPA(1, 8, bc2, bc3); STEPA(2, 8, bc2, bc3);
    STEPA(3, 8, bc2, bc3); STEPA(4, 8, bc2, bc3); STEPA(5, 8, bc2, bc3);
    STEPA(6, 4, bc2, bc3); STEPA(7, 0, bc2, bc3);

    // G-write half 1 + issue the wave's 8 W loads (2 per sub-tile)
#pragma unroll
    for (int i = 0; i < 2; ++i) {
#pragma unroll
        for (int j = 0; j < 2; ++j) {
            int p = (2 * rg + i) * 8 + 4 * tg + 2 + j;
            unsigned prow = (unsigned)p * 2048;
#pragma unroll
            for (int q = 0; q < 4; ++q) {
                int Lc = lane * 4 + q;
                int P = Lc ^ (p & 15) ^ (lane & 7);
                *(bf16x4*)((char*)Gs + prow + (unsigned)P * 16 + kh * 8) =
                    cvt4(acc[i][j][4 * q + 0], acc[i][j][4 * q + 1],
                         acc[i][j][4 * q + 2], acc[i][j][4 * q + 3]);
            }
            {
                const int u = i * 2 + j;   // 0..3
                asm volatile("global_load_dwordx4 %0, %1, off"
                             : "=v"(Wp[2 * u]) : "v"(wbc + (size_t)(kq * 32 + 2 * u) * 4096));
                asm volatile("global_load_dwordx4 %0, %1, off"
                             : "=v"(Wp[2 * u + 1]) : "v"(wbc + (size_t)(kq * 32 + 2 * u + 1) * 4096));
            }
        }
    }

    // Phase boundary: drain LDS ops only; W loads remain in flight.
    asm volatile("s_waitcnt lgkmcnt(0)" ::: "memory");
    __builtin_amdgcn_s_barrier();
    __builtin_amdgcn_sched_barrier(0);

    // ---------------- Phase B (both M-tiles, K-half, counted-vmcnt W window) ----------------
    const unsigned prow0 = (unsigned)lane * 2048;
    const unsigned prow1 = (unsigned)(lane + 32) * 2048;
    const int p15 = lane & 15;

    f32x16 o0, o1;
#pragma unroll
    for (int q = 0; q < 16; ++q) { o0[q] = 0.f; o1[q] = 0.f; }

    bf16x8 Gp[4][2];
#define LDG(sl, j) do { \
    int Lr = (kq * 32 + (j)) * 2 + kh; \
    int P = Lr ^ p15 ^ ((Lr >> 2) & 7); \
    Gp[sl][0] = *(const bf16x8*)((const char*)Gs + prow0 + (unsigned)P * 16); \
    Gp[sl][1] = *(const bf16x8*)((const char*)Gs + prow1 + (unsigned)P * 16); } while (0)

    LDG(0, 0); LDG(1, 1); LDG(2, 2); LDG(3, 3);

#define STEPB(j, cnt) do { \
    asm volatile("s_waitcnt vmcnt(" #cnt ")"); \
    __builtin_amdgcn_sched_barrier(0); \
    __builtin_amdgcn_s_setprio(1); \
    o0 = MFMA(Gp[(j) & 3][0], Wp[(j) & 7], o0, 0, 0, 0); \
    o1 = MFMA(Gp[(j) & 3][1], Wp[(j) & 7], o1, 0, 0, 0); \
    __builtin_amdgcn_s_setprio(0); \
    if ((j) + 8 < 32) { \
        asm volatile("global_load_dwordx4 %0, %1, off" \
                     : "=v"(Wp[(j) & 7]) \
                     : "v"(wbc + (size_t)(kq * 32 + (j) + 8) * 4096)); \
    } \
    if ((j) + 4 < 32) LDG((j) & 3, (j) + 4); \
} while (0)

    STEPB(0, 7);  STEPB(1, 7);  STEPB(2, 7);  STEPB(3, 7);
    STEPB(4, 7);  STEPB(5, 7);  STEPB(6, 7);  STEPB(7, 7);
    STEPB(8, 7);  STEPB(9, 7);  STEPB(10, 7); STEPB(11, 7);
    STEPB(12, 7); STEPB(13, 7); STEPB(14, 7); STEPB(15, 7);
    STEPB(16, 7); STEPB(17, 7); STEPB(18, 7); STEPB(19, 7);
    STEPB(20, 7); STEPB(21, 7); STEPB(22, 7); STEPB(23, 7);
    STEPB(24, 7); STEPB(25, 6); STEPB(26, 5); STEPB(27, 4);
    STEPB(28, 3); STEPB(29, 2); STEPB(30, 1); STEPB(31, 0);

    // all G reads done block-wide before partials overwrite the region
    asm volatile("s_waitcnt lgkmcnt(0)");
    __builtin_amdgcn_s_barrier();

    // 2-way K reduction: region (ng*2 + tile) * 4 KB, layout [pc][l] x 16B
    if (kq == 1) {
        char* p0 = (char*)Gs + (size_t)(ng * 2 + 0) * 4096;
        char* p1 = (char*)Gs + (size_t)(ng * 2 + 1) * 4096;
#pragma unroll
        for (int pc = 0; pc < 4; ++pc) {
            f32x4 v0, v1;
            v0[0] = o0[4 * pc + 0]; v0[1] = o0[4 * pc + 1];
            v0[2] = o0[4 * pc + 2]; v0[3] = o0[4 * pc + 3];
            v1[0] = o1[4 * pc + 0]; v1[1] = o1[4 * pc + 1];
            v1[2] = o1[4 * pc + 2]; v1[3] = o1[4 * pc + 3];
            *(f32x4*)(p0 + (pc * 64 + l) * 16) = v0;
            *(f32x4*)(p1 + (pc * 64 + l) * 16) = v1;
        }
    }
    asm volatile("s_waitcnt lgkmcnt(0)");
    __builtin_amdgcn_s_barrier();

    if (kq == 0) {
        const char* p0 = (const char*)Gs + (size_t)(ng * 2 + 0) * 4096;
        const char* p1 = (const char*)Gs + (size_t)(ng * 2 + 1) * 4096;
#pragma unroll
        for (int pc = 0; pc < 4; ++pc) {
            f32x4 v0 = *(const f32x4*)(p0 + (pc * 64 + l) * 16);
            f32x4 v1 = *(const f32x4*)(p1 + (pc * 64 + l) * 16);
            o0[4 * pc + 0] += v0[0]; o0[4 * pc + 1] += v0[1];
            o0[4 * pc + 2] += v0[2]; o0[4 * pc + 3] += v0[3];
            o1[4 * pc + 0] += v1[0]; o1[4 * pc + 1] += v1[1];
            o1[4 * pc + 2] += v1[2]; o1[4 * pc + 3] += v1[3];
        }
#pragma unroll
        for (int reg = 0; reg < 16; ++reg) {
            int pl = (reg & 3) + 8 * (reg >> 2) + 4 * kh;   // 0..31 within tile
            int p0r = pl, p1r = 32 + pl;
            out[((size_t)(r0 + (p0r >> 3)) * 256 + (t0 + (p0r & 7))) * 128 + czl] = o0[reg];
            out[((size_t)(r0 + (p1r >> 3)) * 256 + (t0 + (p1r & 7))) * 128 + czl] = o1[reg];
        }
    }
}

extern "C" void kernel_launch(void* const* d_in, const int* in_sizes, int n_in,
                              void* d_out, int out_size, void* d_ws, size_t ws_size,
                              hipStream_t stream) {
    const float* msa = (const float*)d_in[0];
    const float* left = (const float*)d_in[1];
    const float* right = (const float*)d_in[2];
    const float* W = (const float*)d_in[3];

    __bf16* aTf = (__bf16*)d_ws;                        // 2 MB
    __bf16* bTf = aTf + (size_t)R * 4096;               // 2 MB
    __bf16* WTf = bTf + (size_t)R * 4096;               // 256 KB
    __bf16* WLRT = WTf + (size_t)128 * 1024;            // 32 KB
    float* outp = (float*)d_out;

    k_wlr<<<64, 256, 0, stream>>>(left, right, WLRT);
    k_projw<<<1536, 256, 0, stream>>>(msa, WLRT, W, aTf, bTf, WTf);
    k_main<<<dim3(32, 32), 512, 0, stream>>>(aTf, bTf, WTf, outp);
}

// Round 21
// 58.091 us; speedup vs baseline: 1.0235x; 1.0235x over previous
//
#include <hip/hip_runtime.h>

typedef __bf16 bf16x8 __attribute__((ext_vector_type(8)));
typedef __bf16 bf16x4 __attribute__((ext_vector_type(4)));
typedef float f32x16 __attribute__((ext_vector_type(16)));
typedef float f32x4 __attribute__((ext_vector_type(4)));

constexpr int S = 128, R = 256, CM = 256, C = 32, CZ = 128;

#define MFMA __builtin_amdgcn_mfma_f32_32x32x16_bf16

__device__ __forceinline__ bf16x4 cvt4(float a, float b, float c, float d) {
    bf16x4 r;
    r[0] = (__bf16)a; r[1] = (__bf16)b; r[2] = (__bf16)c; r[3] = (__bf16)d;
    return r;
}

// K0: WLRT[c][m], c<32 -> left[m][c], else right[m][c-32] (64 blocks, tiny).
__global__ __launch_bounds__(256) void k_wlr(const float* __restrict__ Lp,
                                             const float* __restrict__ Rp,
                                             __bf16* __restrict__ WLRT) {
    int c = blockIdx.x;
    int m = threadIdx.x;
    const float* src = (c < 32) ? Lp : Rp;
    WLRT[(size_t)c * 256 + m] = (__bf16)src[(size_t)m * 32 + (c & 31)];
}

// K1 merged: blocks 0..1023 = projection (r = b>>2, sq = b&3);
// blocks 1024..1535 = W fragment-pack transpose (independent, consumed by k_main).
__global__ __launch_bounds__(256) void k_projw(const float* __restrict__ msa,
                                               const __bf16* __restrict__ WLRT,
                                               const float* __restrict__ W,
                                               __bf16* __restrict__ aTf,
                                               __bf16* __restrict__ bTf,
                                               __bf16* __restrict__ WTf) {
    const int b = blockIdx.x;
    if (b >= 1024) {
        int g = (b - 1024) * 256 + threadIdx.x;
        int cz = g & 127;
        int k = g >> 7;
        int e = k >> 5, c = k & 31;
        float v = W[(size_t)(c * 32 + e) * 128 + cz];
        WTf[((size_t)(k >> 3) * 128 + cz) * 8 + (k & 7)] = (__bf16)v;
        return;
    }

    __shared__ __align__(16) __bf16 As[32 * 256];       // 16 KB
    __shared__ __align__(16) char Pp[2 * 4096];         // 8 KB partials
    const int r = b >> 2;
    const int sq = b & 3;
    const int t = threadIdx.x;

#pragma unroll
    for (int it = 0; it < 8; ++it) {
        int idx = it * 256 + t;
        int row = idx >> 6;
        int cg = idx & 63;
        float4 v = *(const float4*)&msa[((size_t)(sq * 32 + row) * R + r) * CM + cg * 4];
        bf16x4 h = cvt4(v.x, v.y, v.z, v.w);
        int P = (cg >> 1) ^ (row & 15);
        *(bf16x4*)((char*)As + row * 512 + P * 16 + (cg & 1) * 8) = h;
    }
    __syncthreads();

    const int w = t >> 6;
    const int l = t & 63;
    const int l31 = t & 31;
    const int kh = (t >> 5) & 1;
    const int sd = w & 1;
    const int ksh = w >> 1;

    f32x16 acc;
#pragma unroll
    for (int q = 0; q < 16; ++q) acc[q] = 0.f;

    const bf16x8* wb = (const bf16x8*)&WLRT[(size_t)(sd * 32 + l31) * 256 + 8 * kh];
    const char* arow = (const char*)As + l31 * 512;

    __builtin_amdgcn_s_setprio(1);
#pragma unroll
    for (int j = 0; j < 8; ++j) {
        int ks = ksh * 8 + j;
        int P = (2 * ks + kh) ^ (l31 & 15);
        bf16x8 af = *(const bf16x8*)(arow + P * 16);
        acc = MFMA(af, wb[2 * ks], acc, 0, 0, 0);
    }
    __builtin_amdgcn_s_setprio(0);

    char* pbase = Pp + (size_t)sd * 4096;
    if (ksh == 1) {
#pragma unroll
        for (int pc = 0; pc < 4; ++pc) {
            f32x4 v;
            v[0] = acc[4 * pc + 0]; v[1] = acc[4 * pc + 1];
            v[2] = acc[4 * pc + 2]; v[3] = acc[4 * pc + 3];
            *(f32x4*)(pbase + ((pc * 64) + l) * 16) = v;
        }
    }
    __syncthreads();
    if (ksh == 0) {
#pragma unroll
        for (int pc = 0; pc < 4; ++pc) {
            f32x4 v = *(const f32x4*)(pbase + ((pc * 64) + l) * 16);
            acc[4 * pc + 0] += v[0]; acc[4 * pc + 1] += v[1];
            acc[4 * pc + 2] += v[2]; acc[4 * pc + 3] += v[3];
        }
        __bf16* dst = sd ? bTf : aTf;
#pragma unroll
        for (int q = 0; q < 4; ++q) {
            size_t base = (size_t)r * 4096 + (size_t)(2 * sq + (q >> 1)) * 512 +
                          (size_t)(q & 1) * 256 + (size_t)l31 * 8 + 4 * kh;
            *(bf16x4*)&dst[base] = cvt4(acc[4 * q + 0], acc[4 * q + 1],
                                        acc[4 * q + 2], acc[4 * q + 3]);
        }
    }
}

// K2 (r19, best measured): 64 pairs (8r x 8t), 512 thr / 8 waves, G in 128 KB LDS.
// Phase A: depth-3 rotating prefetch; G-write issues 8 W loads (rolling window).
// Phase boundary: lgkm-only s_barrier (W loads stay in flight).
// Phase B: waves (kq=w>>2 K-half, ng=w&3 cz-slice), BOTH M-tiles per wave,
// 32 steps x 2 MFMA, W 8-slot counted-vmcnt window, G ds prefetch depth 4.
// 2-way K reduction via small dead-G partials (8 x 4 KB).
__global__ __launch_bounds__(512, 2) void k_main(const __bf16* __restrict__ aTf,
                                                 const __bf16* __restrict__ bTf,
                                                 const __bf16* __restrict__ WTf,
                                                 float* __restrict__ out) {
    __shared__ __align__(16) __bf16 Gs[64 * 1024];   // 128 KB

    const int t = threadIdx.x;
    const int w = t >> 6;              // 0..7
    const int l = t & 63;
    const int lane = l & 31;
    const int kh = l >> 5;
    const int r0 = blockIdx.x * 8;
    const int t0 = blockIdx.y * 8;

    // ---------------- Phase A ----------------
    const int rg = w & 3;
    const int tg = w >> 2;

    f32x16 acc[2][4];
#pragma unroll
    for (int i = 0; i < 2; ++i)
#pragma unroll
        for (int j = 0; j < 4; ++j)
#pragma unroll
            for (int q = 0; q < 16; ++q) acc[i][j][q] = 0.f;

    const bf16x8* ap0 = (const bf16x8*)aTf + ((size_t)(r0 + 2 * rg + 0) * 512 + kh * 32 + lane);
    const bf16x8* ap1 = (const bf16x8*)aTf + ((size_t)(r0 + 2 * rg + 1) * 512 + kh * 32 + lane);
    const bf16x8* bp0 = (const bf16x8*)bTf + ((size_t)(t0 + 4 * tg + 0) * 512 + kh * 32 + lane);
    const bf16x8* bp1 = (const bf16x8*)bTf + ((size_t)(t0 + 4 * tg + 1) * 512 + kh * 32 + lane);
    const bf16x8* bp2 = (const bf16x8*)bTf + ((size_t)(t0 + 4 * tg + 2) * 512 + kh * 32 + lane);
    const bf16x8* bp3 = (const bf16x8*)bTf + ((size_t)(t0 + 4 * tg + 3) * 512 + kh * 32 + lane);

    bf16x8 Ap[3][2], Bp[3][4];
#pragma unroll
    for (int s = 0; s < 3; ++s) {
        Ap[s][0] = ap0[s * 64]; Ap[s][1] = ap1[s * 64];
        Bp[s][0] = bp0[s * 64]; Bp[s][1] = bp1[s * 64];
        Bp[s][2] = bp2[s * 64]; Bp[s][3] = bp3[s * 64];
    }
#pragma unroll
    for (int ks = 0; ks < 8; ++ks) {
        const int s = ks % 3;
        __builtin_amdgcn_s_setprio(1);
        acc[0][0] = MFMA(Ap[s][0], Bp[s][0], acc[0][0], 0, 0, 0);
        acc[0][1] = MFMA(Ap[s][0], Bp[s][1], acc[0][1], 0, 0, 0);
        acc[0][2] = MFMA(Ap[s][0], Bp[s][2], acc[0][2], 0, 0, 0);
        acc[0][3] = MFMA(Ap[s][0], Bp[s][3], acc[0][3], 0, 0, 0);
        acc[1][0] = MFMA(Ap[s][1], Bp[s][0], acc[1][0], 0, 0, 0);
        acc[1][1] = MFMA(Ap[s][1], Bp[s][1], acc[1][1], 0, 0, 0);
        acc[1][2] = MFMA(Ap[s][1], Bp[s][2], acc[1][2], 0, 0, 0);
        acc[1][3] = MFMA(Ap[s][1], Bp[s][3], acc[1][3], 0, 0, 0);
        __builtin_amdgcn_s_setprio(0);
        if (ks + 3 < 8) {
            const int kn = ks + 3;
            Ap[s][0] = ap0[kn * 64]; Ap[s][1] = ap1[kn * 64];
            Bp[s][0] = bp0[kn * 64]; Bp[s][1] = bp1[kn * 64];
            Bp[s][2] = bp2[kn * 64]; Bp[s][3] = bp3[kn * 64];
        }
    }

    // -------- G-write interleaved with first 8 W-issues --------
    const int kq = w >> 2;             // K-half 0..1
    const int ng = w & 3;              // cz slice 0..3
    const int czl = ng * 32 + lane;
    const char* wbc = (const char*)WTf + ((size_t)kh * 128 + czl) * 16;

    bf16x8 Wp[8];
#pragma unroll
    for (int i = 0; i < 2; ++i) {
#pragma unroll
        for (int j = 0; j < 4; ++j) {
            int p = (2 * rg + i) * 8 + 4 * tg + j;
            unsigned prow = (unsigned)p * 2048;
#pragma unroll
            for (int q = 0; q < 4; ++q) {
                int Lc = lane * 4 + q;
                int P = Lc ^ (p & 15) ^ (lane & 7);
                *(bf16x4*)((char*)Gs + prow + (unsigned)P * 16 + kh * 8) =
                    cvt4(acc[i][j][4 * q + 0], acc[i][j][4 * q + 1],
                         acc[i][j][4 * q + 2], acc[i][j][4 * q + 3]);
            }
            {
                const int u = i * 4 + j;   // 0..7
                asm volatile("global_load_dwordx4 %0, %1, off"
                             : "=v"(Wp[u]) : "v"(wbc + (size_t)(kq * 32 + u) * 4096));
            }
        }
    }

    // Phase boundary: drain LDS ops only; W loads remain in flight.
    asm volatile("s_waitcnt lgkmcnt(0)" ::: "memory");
    __builtin_amdgcn_s_barrier();
    __builtin_amdgcn_sched_barrier(0);

    // ---------------- Phase B (both M-tiles, K-half, counted-vmcnt W window) ----------------
    const unsigned prow0 = (unsigned)lane * 2048;
    const unsigned prow1 = (unsigned)(lane + 32) * 2048;
    const int p15 = lane & 15;

    f32x16 o0, o1;
#pragma unroll
    for (int q = 0; q < 16; ++q) { o0[q] = 0.f; o1[q] = 0.f; }

    bf16x8 Gp[4][2];
#define LDG(sl, j) do { \
    int Lr = (kq * 32 + (j)) * 2 + kh; \
    int P = Lr ^ p15 ^ ((Lr >> 2) & 7); \
    Gp[sl][0] = *(const bf16x8*)((const char*)Gs + prow0 + (unsigned)P * 16); \
    Gp[sl][1] = *(const bf16x8*)((const char*)Gs + prow1 + (unsigned)P * 16); } while (0)

    LDG(0, 0); LDG(1, 1); LDG(2, 2); LDG(3, 3);

#define STEPB(j, cnt) do { \
    asm volatile("s_waitcnt vmcnt(" #cnt ")"); \
    __builtin_amdgcn_sched_barrier(0); \
    __builtin_amdgcn_s_setprio(1); \
    o0 = MFMA(Gp[(j) & 3][0], Wp[(j) & 7], o0, 0, 0, 0); \
    o1 = MFMA(Gp[(j) & 3][1], Wp[(j) & 7], o1, 0, 0, 0); \
    __builtin_amdgcn_s_setprio(0); \
    if ((j) + 8 < 32) { \
        asm volatile("global_load_dwordx4 %0, %1, off" \
                     : "=v"(Wp[(j) & 7]) \
                     : "v"(wbc + (size_t)(kq * 32 + (j) + 8) * 4096)); \
    } \
    if ((j) + 4 < 32) LDG((j) & 3, (j) + 4); \
} while (0)

    STEPB(0, 7);  STEPB(1, 7);  STEPB(2, 7);  STEPB(3, 7);
    STEPB(4, 7);  STEPB(5, 7);  STEPB(6, 7);  STEPB(7, 7);
    STEPB(8, 7);  STEPB(9, 7);  STEPB(10, 7); STEPB(11, 7);
    STEPB(12, 7); STEPB(13, 7); STEPB(14, 7); STEPB(15, 7);
    STEPB(16, 7); STEPB(17, 7); STEPB(18, 7); STEPB(19, 7);
    STEPB(20, 7); STEPB(21, 7); STEPB(22, 7); STEPB(23, 7);
    STEPB(24, 7); STEPB(25, 6); STEPB(26, 5); STEPB(27, 4);
    STEPB(28, 3); STEPB(29, 2); STEPB(30, 1); STEPB(31, 0);

    // all G reads done block-wide before partials overwrite the region
    asm volatile("s_waitcnt lgkmcnt(0)");
    __builtin_amdgcn_s_barrier();

    // 2-way K reduction: region (ng*2 + tile) * 4 KB, layout [pc][l] x 16B
    if (kq == 1) {
        char* p0 = (char*)Gs + (size_t)(ng * 2 + 0) * 4096;
        char* p1 = (char*)Gs + (size_t)(ng * 2 + 1) * 4096;
#pragma unroll
        for (int pc = 0; pc < 4; ++pc) {
            f32x4 v0, v1;
            v0[0] = o0[4 * pc + 0]; v0[1] = o0[4 * pc + 1];
            v0[2] = o0[4 * pc + 2]; v0[3] = o0[4 * pc + 3];
            v1[0] = o1[4 * pc + 0]; v1[1] = o1[4 * pc + 1];
            v1[2] = o1[4 * pc + 2]; v1[3] = o1[4 * pc + 3];
            *(f32x4*)(p0 + (pc * 64 + l) * 16) = v0;
            *(f32x4*)(p1 + (pc * 64 + l) * 16) = v1;
        }
    }
    asm volatile("s_waitcnt lgkmcnt(0)");
    __builtin_amdgcn_s_barrier();

    if (kq == 0) {
        const char* p0 = (const char*)Gs + (size_t)(ng * 2 + 0) * 4096;
        const char* p1 = (const char*)Gs + (size_t)(ng * 2 + 1) * 4096;
#pragma unroll
        for (int pc = 0; pc < 4; ++pc) {
            f32x4 v0 = *(const f32x4*)(p0 + (pc * 64 + l) * 16);
            f32x4 v1 = *(const f32x4*)(p1 + (pc * 64 + l) * 16);
            o0[4 * pc + 0] += v0[0]; o0[4 * pc + 1] += v0[1];
            o0[4 * pc + 2] += v0[2]; o0[4 * pc + 3] += v0[3];
            o1[4 * pc + 0] += v1[0]; o1[4 * pc + 1] += v1[1];
            o1[4 * pc + 2] += v1[2]; o1[4 * pc + 3] += v1[3];
        }
#pragma unroll
        for (int reg = 0; reg < 16; ++reg) {
            int pl = (reg & 3) + 8 * (reg >> 2) + 4 * kh;   // 0..31 within tile
            int p0r = pl, p1r = 32 + pl;
            out[((size_t)(r0 + (p0r >> 3)) * 256 + (t0 + (p0r & 7))) * 128 + czl] = o0[reg];
            out[((size_t)(r0 + (p1r >> 3)) * 256 + (t0 + (p1r & 7))) * 128 + czl] = o1[reg];
        }
    }
}

extern "C" void kernel_launch(void* const* d_in, const int* in_sizes, int n_in,
                              void* d_out, int out_size, void* d_ws, size_t ws_size,
                              hipStream_t stream) {
    const float* msa = (const float*)d_in[0];
    const float* left = (const float*)d_in[1];
    const float* right = (const float*)d_in[2];
    const float* W = (const float*)d_in[3];

    __bf16* aTf = (__bf16*)d_ws;                        // 2 MB
    __bf16* bTf = aTf + (size_t)R * 4096;               // 2 MB
    __bf16* WTf = bTf + (size_t)R * 4096;               // 256 KB
    __bf16* WLRT = WTf + (size_t)128 * 1024;            // 32 KB
    float* outp = (float*)d_out;

    k_wlr<<<64, 256, 0, stream>>>(left, right, WLRT);
    k_projw<<<1536, 256, 0, stream>>>(msa, WLRT, W, aTf, bTf, WTf);
    k_main<<<dim3(32, 32), 512, 0, stream>>>(aTf, bTf, WTf, outp);
}